// Round 3
// baseline (1064.533 us; speedup 1.0000x reference)
//
#include <hip/hip_runtime.h>
#include <hip/hip_bf16.h>
#include <stdint.h>

// Binarized MLP: B=8192, D_IN=3072, H=2000 (pad 2048), C=10.
// Layers 2-4: bf16 MFMA of {0,1}x{+-1} -> EXACT integer accumulation; z in double.
// Layer 1 (exact, memory-lean): Q=round(x*2^14)=d1*512+d0 with d0,d1,d1*512 all
// exact bf16. One K=6144 GEMM over [d1*512|d0] vs [signW|signW] gives Ti=sum(Q*s)
// EXACTLY in fp32 (integer partials < 2^24 whp). Residual r=x-Q*2^-14 (exact fp32
// sub) in one K=3072 GEMM; epilogue combines z1 = mean|W1|*2^-14*(Ti+Sr)+b1 in
// double. Workspace kept at 264 MiB (round-2's 516 MiB overran ws -> GPU fault).
typedef __bf16 bf16_t;
typedef __attribute__((ext_vector_type(8))) __bf16 bf16x8;
typedef __attribute__((ext_vector_type(4))) float f32x4;

#define GLD_LDS16(g, l) __builtin_amdgcn_global_load_lds( \
    (__attribute__((address_space(1))) void*)(g), \
    (__attribute__((address_space(3))) void*)(l), 16, 0, 0)

__device__ __forceinline__ void block_reduce_atomic_d(double v, double* dst) {
    #pragma unroll
    for (int off = 32; off > 0; off >>= 1) v += __shfl_down(v, off);
    __shared__ double rb[4];
    const int t = threadIdx.x;
    if ((t & 63) == 0) rb[t >> 6] = v;
    __syncthreads();
    if (t == 0) atomicAdd(dst, rb[0] + rb[1] + rb[2] + rb[3]);
}

// sign(W) -> bf16 {+-1,0} padded [2048][ldS]; atomic double sum |W|.
// dupOff!=0 duplicates the sign block at column offset dupOff (for [s|s] layout).
__global__ __launch_bounds__(256) void prep_w(
    const float* __restrict__ W, int rows, int cols,
    bf16_t* __restrict__ S, int ldS, int halfW, int dupOff,
    double* __restrict__ sumOut)
{
    const int r = blockIdx.x;      // 0..2047
    const int t = threadIdx.x;
    double sl = 0.0;
    for (int cb = t * 8; cb < halfW; cb += 2048) {
        bf16x8 o;
        if (r < rows) {
            #pragma unroll
            for (int j = 0; j < 8; ++j) {
                int c = cb + j;
                float v = (c < cols) ? W[(size_t)r * cols + c] : 0.f;
                sl += (double)fabsf(v);
                o[j] = (bf16_t)(v > 0.f ? 1.f : (v < 0.f ? -1.f : 0.f));
            }
        } else {
            #pragma unroll
            for (int j = 0; j < 8; ++j) o[j] = (bf16_t)0.f;
        }
        *(bf16x8*)&S[(size_t)r * ldS + cb] = o;
        if (dupOff) *(bf16x8*)&S[(size_t)r * ldS + dupOff + cb] = o;
    }
    block_reduce_atomic_d(sl, sumOut);
}

// x fp32 [8192][3072] -> XLi bf16 [8192][6144] = [d1*512 | d0], XLr bf16 [8192][3072].
__global__ __launch_bounds__(256) void prep_x(
    const float* __restrict__ x, bf16_t* __restrict__ XLi, bf16_t* __restrict__ XLr)
{
    const int r = blockIdx.x, t = threadIdx.x;
    for (int cb = t * 4; cb < 3072; cb += 1024) {
        float4 v = *(const float4*)&x[(size_t)r * 3072 + cb];
        float xv[4] = {v.x, v.y, v.z, v.w};
        bf16_t hi[4], lo[4], re[4];
        #pragma unroll
        for (int j = 0; j < 4; ++j) {
            int Q = (int)lrintf(xv[j] * 16384.f);           // x * 2^14
            int d0 = ((Q + 256) & 511) - 256;               // [-256,255], exact bf16
            int d1 = (Q - d0) / 512;                        // |d1|<=~182, exact bf16
            float rr = xv[j] - (float)Q * (1.f / 16384.f);  // exact (Sterbenz)
            hi[j] = (bf16_t)(float)(d1 * 512);              // exact (shift)
            lo[j] = (bf16_t)(float)d0;
            re[j] = (bf16_t)(rr * 16384.f);                 // in [-.5,.5], only rounding
        }
        size_t bi = (size_t)r * 6144 + cb;
        size_t br = (size_t)r * 3072 + cb;
        #pragma unroll
        for (int j = 0; j < 4; ++j) {
            XLi[bi + j]        = hi[j];
            XLi[bi + 3072 + j] = lo[j];
            XLr[br + j]        = re[j];
        }
    }
}

// C = A @ B^T, A:[8192][K] (row stride K), B:[2048][ldB] bf16. 128x128x64 tiles.
// rawOut mode: write fp32 acc. Otherwise double epilogue:
//   z = sumW*invDivW*(sumH?sumH*invDivH:1)*extraScale*(acc + addPlane?) + bias
//   h = relu(z); optional bin{0,1} bf16 out, fp32 h out, atomic double sum(h).
__global__ __launch_bounds__(256, 2) void gemm_bin(
    const bf16_t* __restrict__ A, const bf16_t* __restrict__ B, int K, int ldB,
    float* __restrict__ rawOut,
    const float* __restrict__ addPlane,
    const double* __restrict__ sumW, double invDivW,
    const double* __restrict__ sumH, double invDivH, double extraScale,
    const float* __restrict__ bias,
    bf16_t* __restrict__ binOut, float* __restrict__ hOut,
    double* __restrict__ habs)
{
    __shared__ __align__(16) bf16_t sA[128 * 64];
    __shared__ __align__(16) bf16_t sB[128 * 64];
    const int t = threadIdx.x;
    const int lane = t & 63;
    const int wave = t >> 6;
    const int wr = wave >> 1, wc = wave & 1;
    const int qa = lane >> 4, rA = lane & 15;
    const size_t bm = (size_t)blockIdx.y * 128, bn = (size_t)blockIdx.x * 128;

    f32x4 acc[4][4] = {};

    const bf16_t* Abase = A + bm * (size_t)K;
    const bf16_t* Bbase = B + bn * (size_t)ldB;

    const int swz = rA & 7;
    const int offk0 = ((0 + qa) ^ swz) * 8;
    const int offk1 = ((4 + qa) ^ swz) * 8;
    const int arow = wr * 64 + rA;
    const int brow = wc * 64 + rA;

    for (int k0 = 0; k0 < K; k0 += 64) {
        #pragma unroll
        for (int i = 0; i < 4; ++i) {
            int c = i * 256 + t;
            int row = c >> 3, cc = c & 7;
            int ccg = cc ^ (row & 7);
            GLD_LDS16(Abase + (size_t)row * K + k0 + ccg * 8, &sA[c * 8]);
        }
        #pragma unroll
        for (int i = 0; i < 4; ++i) {
            int c = i * 256 + t;
            int row = c >> 3, cc = c & 7;
            int ccg = cc ^ (row & 7);
            GLD_LDS16(Bbase + (size_t)row * ldB + k0 + ccg * 8, &sB[c * 8]);
        }
        __syncthreads();

        bf16x8 fa[4][2], fb[4][2];
        #pragma unroll
        for (int i = 0; i < 4; ++i) {
            fa[i][0] = *(const bf16x8*)&sA[(arow + i * 16) * 64 + offk0];
            fa[i][1] = *(const bf16x8*)&sA[(arow + i * 16) * 64 + offk1];
            fb[i][0] = *(const bf16x8*)&sB[(brow + i * 16) * 64 + offk0];
            fb[i][1] = *(const bf16x8*)&sB[(brow + i * 16) * 64 + offk1];
        }
        #pragma unroll
        for (int i = 0; i < 4; ++i)
            #pragma unroll
            for (int j = 0; j < 4; ++j) {
                acc[i][j] = __builtin_amdgcn_mfma_f32_16x16x32_bf16(fa[i][0], fb[j][0], acc[i][j], 0, 0, 0);
                acc[i][j] = __builtin_amdgcn_mfma_f32_16x16x32_bf16(fa[i][1], fb[j][1], acc[i][j], 0, 0, 0);
            }
        __syncthreads();
    }

    if (rawOut) {   // exact integer partial sums in fp32
        #pragma unroll
        for (int i = 0; i < 4; ++i)
            #pragma unroll
            for (int j = 0; j < 4; ++j)
                #pragma unroll
                for (int rr = 0; rr < 4; ++rr) {
                    int m = (int)bm + wr * 64 + i * 16 + qa * 4 + rr;
                    int n = (int)bn + wc * 64 + j * 16 + rA;
                    rawOut[(size_t)m * 2048 + n] = acc[i][j][rr];
                }
        return;
    }

    const double scale = sumW[0] * invDivW * (sumH ? sumH[0] * invDivH : 1.0) * extraScale;
    double hs = 0.0;
    #pragma unroll
    for (int i = 0; i < 4; ++i) {
        #pragma unroll
        for (int j = 0; j < 4; ++j) {
            #pragma unroll
            for (int rr = 0; rr < 4; ++rr) {
                // C/D layout: col = lane&15, row = (lane>>4)*4 + reg
                int m = (int)bm + wr * 64 + i * 16 + qa * 4 + rr;
                int n = (int)bn + wc * 64 + j * 16 + rA;
                size_t idx = (size_t)m * 2048 + n;
                double s = (double)acc[i][j][rr];
                if (addPlane) s += (double)addPlane[idx];
                double z = s * scale + (n < 2000 ? (double)bias[n] : -1.0);
                double h = z > 0.0 ? z : 0.0;
                if (binOut) binOut[idx] = (bf16_t)(z > 0.0 ? 1.f : 0.f);
                if (hOut)   hOut[idx] = (float)h;
                if (n < 2000) hs += h;
            }
        }
    }
    if (habs) block_reduce_atomic_d(hs, habs);
}

// out[8192][10] = h4[:, :2000] @ W5.T + b5  (fp32, memory-bound)
__global__ __launch_bounds__(256) void fc_final(
    const float* __restrict__ h4, const float* __restrict__ W5,
    const float* __restrict__ b5, float* __restrict__ out)
{
    const int r = blockIdx.x, t = threadIdx.x;
    float acc[10] = {};
    for (int k = t; k < 2000; k += 256) {
        float a = h4[(size_t)r * 2048 + k];
        #pragma unroll
        for (int c = 0; c < 10; ++c) acc[c] += a * W5[c * 2000 + k];
    }
    __shared__ float red[4][10];
    #pragma unroll
    for (int c = 0; c < 10; ++c) {
        float v = acc[c];
        #pragma unroll
        for (int off = 32; off > 0; off >>= 1) v += __shfl_down(v, off);
        if ((t & 63) == 0) red[t >> 6][c] = v;
    }
    __syncthreads();
    if (t < 10) out[(size_t)r * 10 + t] = red[0][t] + red[1][t] + red[2][t] + red[3][t] + b5[t];
}

extern "C" void kernel_launch(void* const* d_in, const int* in_sizes, int n_in,
                              void* d_out, int out_size, void* d_ws, size_t ws_size,
                              hipStream_t stream)
{
    const float* x  = (const float*)d_in[0];
    const float* W1 = (const float*)d_in[1];
    const float* b1 = (const float*)d_in[2];
    const float* W2 = (const float*)d_in[3];
    const float* b2 = (const float*)d_in[4];
    const float* W3 = (const float*)d_in[5];
    const float* b3 = (const float*)d_in[6];
    const float* W4 = (const float*)d_in[7];
    const float* b4 = (const float*)d_in[8];
    const float* W5 = (const float*)d_in[9];
    const float* b5 = (const float*)d_in[10];
    float* out = (float*)d_out;
    (void)ws_size; (void)in_sizes; (void)n_in; (void)out_size;

    const size_t PH = (size_t)8192 * 2048;

    // Workspace: 264.3 MiB total (round-1's 271.6 MiB executed; round-2's 516 faulted)
    char* w = (char*)d_ws;
    double* scD = (double*)w;                     // [0..3]=sum|W1..4|, [4..6]=sum h1..3
    size_t off = 256;
    bf16_t* XLi = (bf16_t*)(w + off); off += (size_t)8192 * 6144 * 2;  // 96 MiB
    bf16_t* XLr = (bf16_t*)(w + off); off += (size_t)8192 * 3072 * 2;  // 48 MiB
    bf16_t* sW1 = (bf16_t*)(w + off); off += (size_t)2048 * 6144 * 2;  // 24 MiB [s|s]
    float*  Ti  = (float*)(w + off);  off += PH * 4;                   // 64 MiB
    bf16_t* p0  = (bf16_t*)(w + off); off += PH * 2;                   // 32 MiB
    // Aliases into XLi (dead after the two L1 GEMMs): sW2,sW3,sW4 (24 MiB) + p1 (32 MiB)
    bf16_t* sW2 = XLi;
    bf16_t* sW3 = XLi + (size_t)2048 * 2048;
    bf16_t* sW4 = XLi + (size_t)2 * 2048 * 2048;
    bf16_t* p1  = XLi + (size_t)3 * 2048 * 2048;
    float*  h4  = Ti;                              // Ti dead after GEMM-res epilogue

    hipMemsetAsync(w, 0, 256, stream);
    prep_w<<<2048, 256, 0, stream>>>(W1, 2000, 3072, sW1, 6144, 3072, 3072, scD + 0);
    prep_x<<<8192, 256, 0, stream>>>(x, XLi, XLr);

    dim3 grid(16, 64), blk(256);
    // L1 integer GEMM (exact): Ti = [d1*512|d0] @ [s|s]^T
    gemm_bin<<<grid, blk, 0, stream>>>(XLi, sW1, 6144, 6144, Ti, nullptr,
                                       nullptr, 0.0, nullptr, 0.0, 1.0,
                                       nullptr, nullptr, nullptr, nullptr);
    // L1 residual GEMM + fused combine: z1 = mean|W1| * 2^-14 * (Ti + Sr) + b1
    gemm_bin<<<grid, blk, 0, stream>>>(XLr, sW1, 3072, 6144, nullptr, Ti,
                                       scD + 0, 1.0 / 6144000.0, nullptr, 0.0, 1.0 / 16384.0,
                                       b1, p0, nullptr, scD + 4);
    // prep remaining weight signs into the now-dead XLi region
    prep_w<<<2048, 256, 0, stream>>>(W2, 2000, 2000, sW2, 2048, 2048, 0, scD + 1);
    prep_w<<<2048, 256, 0, stream>>>(W3, 2000, 2000, sW3, 2048, 2048, 0, scD + 2);
    prep_w<<<2048, 256, 0, stream>>>(W4, 2000, 2000, sW4, 2048, 2048, 0, scD + 3);

    // Layers 2-4: exact integer GEMMs, double epilogue
    gemm_bin<<<grid, blk, 0, stream>>>(p0, sW2, 2048, 2048, nullptr, nullptr,
                                       scD + 1, 1.0 / 4000000.0, scD + 4, 1.0 / 16384000.0, 1.0,
                                       b2, p1, nullptr, scD + 5);
    gemm_bin<<<grid, blk, 0, stream>>>(p1, sW3, 2048, 2048, nullptr, nullptr,
                                       scD + 2, 1.0 / 4000000.0, scD + 5, 1.0 / 16384000.0, 1.0,
                                       b3, p0, nullptr, scD + 6);
    gemm_bin<<<grid, blk, 0, stream>>>(p0, sW4, 2048, 2048, nullptr, nullptr,
                                       scD + 3, 1.0 / 4000000.0, scD + 6, 1.0 / 16384000.0, 1.0,
                                       b4, nullptr, h4, nullptr);
    fc_final<<<8192, 256, 0, stream>>>(h4, W5, b5, out);
}

// Round 4
// 1007.220 us; speedup vs baseline: 1.0569x; 1.0569x over previous
//
#include <hip/hip_runtime.h>
#include <hip/hip_bf16.h>
#include <stdint.h>

// Binarized MLP: B=8192, D_IN=3072, H=2000 (pad 2048), C=10.
// Layers 2-4: bf16 MFMA of {0,1}x{+-1} -> EXACT integer accumulation; z in double.
// Layer 1 (exact): Q=round(x*2^14)=d1*512+d0, all digits exact in bf16.
// K=6144 GEMM [d1*512|d0] vs [signW|signW] -> Ti exact in fp32; residual
// r=x-Q*2^-14 in K=3072 GEMM; epilogue z1 = mean|W1|*2^-14*(Ti+Sr)+b1 in double.
// R4: launch_bounds (256,2)->(256,4) [occupancy was self-capped at 2 blk/CU
// with VGPR=80, LDS=33KB allowing 4]; prep_x stores vectorized (was 12 scalar
// bf16 stores/iter). Numerics bit-identical to passing R3.
typedef __bf16 bf16_t;
typedef __attribute__((ext_vector_type(8))) __bf16 bf16x8;
typedef __attribute__((ext_vector_type(4))) float f32x4;

#define GLD_LDS16(g, l) __builtin_amdgcn_global_load_lds( \
    (__attribute__((address_space(1))) void*)(g), \
    (__attribute__((address_space(3))) void*)(l), 16, 0, 0)

__device__ __forceinline__ void block_reduce_atomic_d(double v, double* dst) {
    #pragma unroll
    for (int off = 32; off > 0; off >>= 1) v += __shfl_down(v, off);
    __shared__ double rb[4];
    const int t = threadIdx.x;
    if ((t & 63) == 0) rb[t >> 6] = v;
    __syncthreads();
    if (t == 0) atomicAdd(dst, rb[0] + rb[1] + rb[2] + rb[3]);
}

// sign(W) -> bf16 {+-1,0} padded [2048][ldS]; atomic double sum |W|.
// dupOff!=0 duplicates the sign block at column offset dupOff (for [s|s] layout).
__global__ __launch_bounds__(256) void prep_w(
    const float* __restrict__ W, int rows, int cols,
    bf16_t* __restrict__ S, int ldS, int halfW, int dupOff,
    double* __restrict__ sumOut)
{
    const int r = blockIdx.x;      // 0..2047
    const int t = threadIdx.x;
    double sl = 0.0;
    for (int cb = t * 8; cb < halfW; cb += 2048) {
        bf16x8 o;
        if (r < rows) {
            #pragma unroll
            for (int j = 0; j < 8; ++j) {
                int c = cb + j;
                float v = (c < cols) ? W[(size_t)r * cols + c] : 0.f;
                sl += (double)fabsf(v);
                o[j] = (bf16_t)(v > 0.f ? 1.f : (v < 0.f ? -1.f : 0.f));
            }
        } else {
            #pragma unroll
            for (int j = 0; j < 8; ++j) o[j] = (bf16_t)0.f;
        }
        *(bf16x8*)&S[(size_t)r * ldS + cb] = o;
        if (dupOff) *(bf16x8*)&S[(size_t)r * ldS + dupOff + cb] = o;
    }
    block_reduce_atomic_d(sl, sumOut);
}

// x fp32 [8192][3072] -> XLi bf16 [8192][6144] = [d1*512 | d0], XLr bf16 [8192][3072].
// 8 cols/thread, 16B vector stores.
__global__ __launch_bounds__(256) void prep_x(
    const float* __restrict__ x, bf16_t* __restrict__ XLi, bf16_t* __restrict__ XLr)
{
    const int r = blockIdx.x, t = threadIdx.x;
    for (int cb = t * 8; cb < 3072; cb += 2048) {
        float4 v0 = *(const float4*)&x[(size_t)r * 3072 + cb];
        float4 v1 = *(const float4*)&x[(size_t)r * 3072 + cb + 4];
        float xv[8] = {v0.x, v0.y, v0.z, v0.w, v1.x, v1.y, v1.z, v1.w};
        bf16x8 hi, lo, re;
        #pragma unroll
        for (int j = 0; j < 8; ++j) {
            int Q = (int)lrintf(xv[j] * 16384.f);           // x * 2^14
            int d0 = ((Q + 256) & 511) - 256;               // [-256,255], exact bf16
            int d1 = (Q - d0) / 512;                        // |d1|<=~182, exact bf16
            float rr = xv[j] - (float)Q * (1.f / 16384.f);  // exact (Sterbenz)
            hi[j] = (bf16_t)(float)(d1 * 512);              // exact (pow2 shift)
            lo[j] = (bf16_t)(float)d0;
            re[j] = (bf16_t)(rr * 16384.f);                 // in [-.5,.5]
        }
        *(bf16x8*)&XLi[(size_t)r * 6144 + cb]        = hi;
        *(bf16x8*)&XLi[(size_t)r * 6144 + 3072 + cb] = lo;
        *(bf16x8*)&XLr[(size_t)r * 3072 + cb]        = re;
    }
}

// C = A @ B^T, A:[8192][K] (row stride K), B:[2048][ldB] bf16. 128x128x64 tiles.
// rawOut mode: write fp32 acc. Otherwise double epilogue:
//   z = sumW*invDivW*(sumH?sumH*invDivH:1)*extraScale*(acc + addPlane?) + bias
//   h = relu(z); optional bin{0,1} bf16 out, fp32 h out, atomic double sum(h).
// launch_bounds(256,4): VGPR=80, LDS=33KB -> 4 blocks/CU reachable.
__global__ __launch_bounds__(256, 4) void gemm_bin(
    const bf16_t* __restrict__ A, const bf16_t* __restrict__ B, int K, int ldB,
    float* __restrict__ rawOut,
    const float* __restrict__ addPlane,
    const double* __restrict__ sumW, double invDivW,
    const double* __restrict__ sumH, double invDivH, double extraScale,
    const float* __restrict__ bias,
    bf16_t* __restrict__ binOut, float* __restrict__ hOut,
    double* __restrict__ habs)
{
    __shared__ __align__(16) bf16_t sA[128 * 64];
    __shared__ __align__(16) bf16_t sB[128 * 64];
    const int t = threadIdx.x;
    const int lane = t & 63;
    const int wave = t >> 6;
    const int wr = wave >> 1, wc = wave & 1;
    const int qa = lane >> 4, rA = lane & 15;
    const size_t bm = (size_t)blockIdx.y * 128, bn = (size_t)blockIdx.x * 128;

    f32x4 acc[4][4] = {};

    const bf16_t* Abase = A + bm * (size_t)K;
    const bf16_t* Bbase = B + bn * (size_t)ldB;

    const int swz = rA & 7;
    const int offk0 = ((0 + qa) ^ swz) * 8;
    const int offk1 = ((4 + qa) ^ swz) * 8;
    const int arow = wr * 64 + rA;
    const int brow = wc * 64 + rA;

    for (int k0 = 0; k0 < K; k0 += 64) {
        #pragma unroll
        for (int i = 0; i < 4; ++i) {
            int c = i * 256 + t;
            int row = c >> 3, cc = c & 7;
            int ccg = cc ^ (row & 7);
            GLD_LDS16(Abase + (size_t)row * K + k0 + ccg * 8, &sA[c * 8]);
        }
        #pragma unroll
        for (int i = 0; i < 4; ++i) {
            int c = i * 256 + t;
            int row = c >> 3, cc = c & 7;
            int ccg = cc ^ (row & 7);
            GLD_LDS16(Bbase + (size_t)row * ldB + k0 + ccg * 8, &sB[c * 8]);
        }
        __syncthreads();

        bf16x8 fa[4][2], fb[4][2];
        #pragma unroll
        for (int i = 0; i < 4; ++i) {
            fa[i][0] = *(const bf16x8*)&sA[(arow + i * 16) * 64 + offk0];
            fa[i][1] = *(const bf16x8*)&sA[(arow + i * 16) * 64 + offk1];
            fb[i][0] = *(const bf16x8*)&sB[(brow + i * 16) * 64 + offk0];
            fb[i][1] = *(const bf16x8*)&sB[(brow + i * 16) * 64 + offk1];
        }
        #pragma unroll
        for (int i = 0; i < 4; ++i)
            #pragma unroll
            for (int j = 0; j < 4; ++j) {
                acc[i][j] = __builtin_amdgcn_mfma_f32_16x16x32_bf16(fa[i][0], fb[j][0], acc[i][j], 0, 0, 0);
                acc[i][j] = __builtin_amdgcn_mfma_f32_16x16x32_bf16(fa[i][1], fb[j][1], acc[i][j], 0, 0, 0);
            }
        __syncthreads();
    }

    if (rawOut) {   // exact integer partial sums in fp32
        #pragma unroll
        for (int i = 0; i < 4; ++i)
            #pragma unroll
            for (int j = 0; j < 4; ++j)
                #pragma unroll
                for (int rr = 0; rr < 4; ++rr) {
                    int m = (int)bm + wr * 64 + i * 16 + qa * 4 + rr;
                    int n = (int)bn + wc * 64 + j * 16 + rA;
                    rawOut[(size_t)m * 2048 + n] = acc[i][j][rr];
                }
        return;
    }

    const double scale = sumW[0] * invDivW * (sumH ? sumH[0] * invDivH : 1.0) * extraScale;
    double hs = 0.0;
    #pragma unroll
    for (int i = 0; i < 4; ++i) {
        #pragma unroll
        for (int j = 0; j < 4; ++j) {
            #pragma unroll
            for (int rr = 0; rr < 4; ++rr) {
                // C/D layout: col = lane&15, row = (lane>>4)*4 + reg
                int m = (int)bm + wr * 64 + i * 16 + qa * 4 + rr;
                int n = (int)bn + wc * 64 + j * 16 + rA;
                size_t idx = (size_t)m * 2048 + n;
                double s = (double)acc[i][j][rr];
                if (addPlane) s += (double)addPlane[idx];
                double z = s * scale + (n < 2000 ? (double)bias[n] : -1.0);
                double h = z > 0.0 ? z : 0.0;
                if (binOut) binOut[idx] = (bf16_t)(z > 0.0 ? 1.f : 0.f);
                if (hOut)   hOut[idx] = (float)h;
                if (n < 2000) hs += h;
            }
        }
    }
    if (habs) block_reduce_atomic_d(hs, habs);
}

// out[8192][10] = h4[:, :2000] @ W5.T + b5  (fp32, memory-bound)
__global__ __launch_bounds__(256) void fc_final(
    const float* __restrict__ h4, const float* __restrict__ W5,
    const float* __restrict__ b5, float* __restrict__ out)
{
    const int r = blockIdx.x, t = threadIdx.x;
    float acc[10] = {};
    for (int k = t; k < 2000; k += 256) {
        float a = h4[(size_t)r * 2048 + k];
        #pragma unroll
        for (int c = 0; c < 10; ++c) acc[c] += a * W5[c * 2000 + k];
    }
    __shared__ float red[4][10];
    #pragma unroll
    for (int c = 0; c < 10; ++c) {
        float v = acc[c];
        #pragma unroll
        for (int off = 32; off > 0; off >>= 1) v += __shfl_down(v, off);
        if ((t & 63) == 0) red[t >> 6][c] = v;
    }
    __syncthreads();
    if (t < 10) out[(size_t)r * 10 + t] = red[0][t] + red[1][t] + red[2][t] + red[3][t] + b5[t];
}

extern "C" void kernel_launch(void* const* d_in, const int* in_sizes, int n_in,
                              void* d_out, int out_size, void* d_ws, size_t ws_size,
                              hipStream_t stream)
{
    const float* x  = (const float*)d_in[0];
    const float* W1 = (const float*)d_in[1];
    const float* b1 = (const float*)d_in[2];
    const float* W2 = (const float*)d_in[3];
    const float* b2 = (const float*)d_in[4];
    const float* W3 = (const float*)d_in[5];
    const float* b3 = (const float*)d_in[6];
    const float* W4 = (const float*)d_in[7];
    const float* b4 = (const float*)d_in[8];
    const float* W5 = (const float*)d_in[9];
    const float* b5 = (const float*)d_in[10];
    float* out = (float*)d_out;
    (void)ws_size; (void)in_sizes; (void)n_in; (void)out_size;

    const size_t PH = (size_t)8192 * 2048;

    // Workspace: 264.3 MiB total (R3 proved this executes; 516 MiB faulted)
    char* w = (char*)d_ws;
    double* scD = (double*)w;                     // [0..3]=sum|W1..4|, [4..6]=sum h1..3
    size_t off = 256;
    bf16_t* XLi = (bf16_t*)(w + off); off += (size_t)8192 * 6144 * 2;  // 96 MiB
    bf16_t* XLr = (bf16_t*)(w + off); off += (size_t)8192 * 3072 * 2;  // 48 MiB
    bf16_t* sW1 = (bf16_t*)(w + off); off += (size_t)2048 * 6144 * 2;  // 24 MiB [s|s]
    float*  Ti  = (float*)(w + off);  off += PH * 4;                   // 64 MiB
    bf16_t* p0  = (bf16_t*)(w + off); off += PH * 2;                   // 32 MiB
    // Aliases into XLi (dead after the two L1 GEMMs): sW2,sW3,sW4 (24 MiB) + p1 (32 MiB)
    bf16_t* sW2 = XLi;
    bf16_t* sW3 = XLi + (size_t)2048 * 2048;
    bf16_t* sW4 = XLi + (size_t)2 * 2048 * 2048;
    bf16_t* p1  = XLi + (size_t)3 * 2048 * 2048;
    float*  h4  = Ti;                              // Ti dead after GEMM-res epilogue

    hipMemsetAsync(w, 0, 256, stream);
    prep_w<<<2048, 256, 0, stream>>>(W1, 2000, 3072, sW1, 6144, 3072, 3072, scD + 0);
    prep_x<<<8192, 256, 0, stream>>>(x, XLi, XLr);

    dim3 grid(16, 64), blk(256);
    // L1 integer GEMM (exact): Ti = [d1*512|d0] @ [s|s]^T
    gemm_bin<<<grid, blk, 0, stream>>>(XLi, sW1, 6144, 6144, Ti, nullptr,
                                       nullptr, 0.0, nullptr, 0.0, 1.0,
                                       nullptr, nullptr, nullptr, nullptr);
    // L1 residual GEMM + fused combine: z1 = mean|W1| * 2^-14 * (Ti + Sr) + b1
    gemm_bin<<<grid, blk, 0, stream>>>(XLr, sW1, 3072, 6144, nullptr, Ti,
                                       scD + 0, 1.0 / 6144000.0, nullptr, 0.0, 1.0 / 16384.0,
                                       b1, p0, nullptr, scD + 4);
    // prep remaining weight signs into the now-dead XLi region
    prep_w<<<2048, 256, 0, stream>>>(W2, 2000, 2000, sW2, 2048, 2048, 0, scD + 1);
    prep_w<<<2048, 256, 0, stream>>>(W3, 2000, 2000, sW3, 2048, 2048, 0, scD + 2);
    prep_w<<<2048, 256, 0, stream>>>(W4, 2000, 2000, sW4, 2048, 2048, 0, scD + 3);

    // Layers 2-4: exact integer GEMMs, double epilogue
    gemm_bin<<<grid, blk, 0, stream>>>(p0, sW2, 2048, 2048, nullptr, nullptr,
                                       scD + 1, 1.0 / 4000000.0, scD + 4, 1.0 / 16384000.0, 1.0,
                                       b2, p1, nullptr, scD + 5);
    gemm_bin<<<grid, blk, 0, stream>>>(p1, sW3, 2048, 2048, nullptr, nullptr,
                                       scD + 2, 1.0 / 4000000.0, scD + 5, 1.0 / 16384000.0, 1.0,
                                       b3, p0, nullptr, scD + 6);
    gemm_bin<<<grid, blk, 0, stream>>>(p0, sW4, 2048, 2048, nullptr, nullptr,
                                       scD + 3, 1.0 / 4000000.0, scD + 6, 1.0 / 16384000.0, 1.0,
                                       b4, nullptr, h4, nullptr);
    fc_final<<<8192, 256, 0, stream>>>(h4, W5, b5, out);
}

// Round 5
// 910.253 us; speedup vs baseline: 1.1695x; 1.1065x over previous
//
#include <hip/hip_runtime.h>
#include <hip/hip_bf16.h>
#include <stdint.h>

// Binarized MLP: B=8192, D_IN=3072, H=2000 (pad 2048), C=10.
// L1 (exact, bf16 MFMA): Q=round(x*2^14)=d1*512+d0 digits exact in bf16;
//   K=6144 GEMM [d1*512|d0]@[s|s]^T -> Ti exact; residual K=3072 GEMM fuses
//   z1 = mean|W1|*2^-14*(Ti+Sr)+b1 in double.
// Layers 2-4 (R5): i8 MFMA (mfma_i32_16x16x64_i8) on {0,1}x{+-1} — exact i32,
//   ~1.9x bf16 rate, BK=128 in same 32KB LDS (half the barriers). h4 in bf16.
typedef __bf16 bf16_t;
typedef __attribute__((ext_vector_type(8))) __bf16 bf16x8;
typedef __attribute__((ext_vector_type(4))) float f32x4;
typedef __attribute__((ext_vector_type(4))) int i32x4;
typedef __attribute__((ext_vector_type(8))) char i8x8;

#define GLD_LDS16(g, l) __builtin_amdgcn_global_load_lds( \
    (__attribute__((address_space(1))) void*)(g), \
    (__attribute__((address_space(3))) void*)(l), 16, 0, 0)

__device__ __forceinline__ void block_reduce_atomic_d(double v, double* dst) {
    #pragma unroll
    for (int off = 32; off > 0; off >>= 1) v += __shfl_down(v, off);
    __shared__ double rb[4];
    const int t = threadIdx.x;
    if ((t & 63) == 0) rb[t >> 6] = v;
    __syncthreads();
    if (t == 0) atomicAdd(dst, rb[0] + rb[1] + rb[2] + rb[3]);
}

// sign(W) -> bf16 {+-1,0} padded [2048][ldS]; atomic double sum |W|.
// dupOff!=0 duplicates the sign block at column offset dupOff ([s|s] layout).
__global__ __launch_bounds__(256) void prep_w(
    const float* __restrict__ W, int rows, int cols,
    bf16_t* __restrict__ S, int ldS, int halfW, int dupOff,
    double* __restrict__ sumOut)
{
    const int r = blockIdx.x;      // 0..2047
    const int t = threadIdx.x;
    double sl = 0.0;
    for (int cb = t * 8; cb < halfW; cb += 2048) {
        bf16x8 o;
        if (r < rows) {
            #pragma unroll
            for (int j = 0; j < 8; ++j) {
                int c = cb + j;
                float v = (c < cols) ? W[(size_t)r * cols + c] : 0.f;
                sl += (double)fabsf(v);
                o[j] = (bf16_t)(v > 0.f ? 1.f : (v < 0.f ? -1.f : 0.f));
            }
        } else {
            #pragma unroll
            for (int j = 0; j < 8; ++j) o[j] = (bf16_t)0.f;
        }
        *(bf16x8*)&S[(size_t)r * ldS + cb] = o;
        if (dupOff) *(bf16x8*)&S[(size_t)r * ldS + dupOff + cb] = o;
    }
    block_reduce_atomic_d(sl, sumOut);
}

// sign(W) -> i8 {+-1,0} padded [2048][2048]; atomic double sum |W|.
__global__ __launch_bounds__(256) void prep_w_i8(
    const float* __restrict__ W, int rows, int cols,
    int8_t* __restrict__ S, double* __restrict__ sumOut)
{
    const int r = blockIdx.x;      // 0..2047
    const int t = threadIdx.x;
    const int cb = t * 8;
    double sl = 0.0;
    i8x8 o;
    if (r < rows) {
        #pragma unroll
        for (int j = 0; j < 8; ++j) {
            int c = cb + j;
            float v = (c < cols) ? W[(size_t)r * cols + c] : 0.f;
            sl += (double)fabsf(v);
            o[j] = (char)(v > 0.f ? 1 : (v < 0.f ? -1 : 0));
        }
    } else {
        #pragma unroll
        for (int j = 0; j < 8; ++j) o[j] = 0;
    }
    *(i8x8*)&S[(size_t)r * 2048 + cb] = o;
    block_reduce_atomic_d(sl, sumOut);
}

// x fp32 [8192][3072] -> XLi bf16 [8192][6144] = [d1*512 | d0], XLr bf16 [8192][3072].
__global__ __launch_bounds__(256) void prep_x(
    const float* __restrict__ x, bf16_t* __restrict__ XLi, bf16_t* __restrict__ XLr)
{
    const int r = blockIdx.x, t = threadIdx.x;
    for (int cb = t * 8; cb < 3072; cb += 2048) {
        float4 v0 = *(const float4*)&x[(size_t)r * 3072 + cb];
        float4 v1 = *(const float4*)&x[(size_t)r * 3072 + cb + 4];
        float xv[8] = {v0.x, v0.y, v0.z, v0.w, v1.x, v1.y, v1.z, v1.w};
        bf16x8 hi, lo, re;
        #pragma unroll
        for (int j = 0; j < 8; ++j) {
            int Q = (int)lrintf(xv[j] * 16384.f);           // x * 2^14
            int d0 = ((Q + 256) & 511) - 256;               // [-256,255], exact bf16
            int d1 = (Q - d0) / 512;                        // |d1|<=~182, exact bf16
            float rr = xv[j] - (float)Q * (1.f / 16384.f);  // exact (Sterbenz)
            hi[j] = (bf16_t)(float)(d1 * 512);              // exact (pow2 shift)
            lo[j] = (bf16_t)(float)d0;
            re[j] = (bf16_t)(rr * 16384.f);                 // in [-.5,.5]
        }
        *(bf16x8*)&XLi[(size_t)r * 6144 + cb]        = hi;
        *(bf16x8*)&XLi[(size_t)r * 6144 + 3072 + cb] = lo;
        *(bf16x8*)&XLr[(size_t)r * 3072 + cb]        = re;
    }
}

// bf16 GEMM C = A @ B^T, 128x128x64 tiles. rawOut mode writes fp32 acc.
// Epilogue (double): z = sumW*invDivW*(sumH?..)*extraScale*(acc+addPlane?) + bias;
// binOut i8 {0,1}; atomic double sum(relu z).
__global__ __launch_bounds__(256, 4) void gemm_bin(
    const bf16_t* __restrict__ A, const bf16_t* __restrict__ B, int K, int ldB,
    float* __restrict__ rawOut,
    const float* __restrict__ addPlane,
    const double* __restrict__ sumW, double invDivW, double extraScale,
    const float* __restrict__ bias,
    int8_t* __restrict__ binOut,
    double* __restrict__ habs)
{
    __shared__ __align__(16) bf16_t sA[128 * 64];
    __shared__ __align__(16) bf16_t sB[128 * 64];
    const int t = threadIdx.x;
    const int lane = t & 63;
    const int wave = t >> 6;
    const int wr = wave >> 1, wc = wave & 1;
    const int qa = lane >> 4, rA = lane & 15;
    const size_t bm = (size_t)blockIdx.y * 128, bn = (size_t)blockIdx.x * 128;

    f32x4 acc[4][4] = {};

    const bf16_t* Abase = A + bm * (size_t)K;
    const bf16_t* Bbase = B + bn * (size_t)ldB;

    const int swz = rA & 7;
    const int offk0 = ((0 + qa) ^ swz) * 8;
    const int offk1 = ((4 + qa) ^ swz) * 8;
    const int arow = wr * 64 + rA;
    const int brow = wc * 64 + rA;

    for (int k0 = 0; k0 < K; k0 += 64) {
        #pragma unroll
        for (int i = 0; i < 4; ++i) {
            int c = i * 256 + t;
            int row = c >> 3, cc = c & 7;
            int ccg = cc ^ (row & 7);
            GLD_LDS16(Abase + (size_t)row * K + k0 + ccg * 8, &sA[c * 8]);
        }
        #pragma unroll
        for (int i = 0; i < 4; ++i) {
            int c = i * 256 + t;
            int row = c >> 3, cc = c & 7;
            int ccg = cc ^ (row & 7);
            GLD_LDS16(Bbase + (size_t)row * ldB + k0 + ccg * 8, &sB[c * 8]);
        }
        __syncthreads();

        bf16x8 fa[4][2], fb[4][2];
        #pragma unroll
        for (int i = 0; i < 4; ++i) {
            fa[i][0] = *(const bf16x8*)&sA[(arow + i * 16) * 64 + offk0];
            fa[i][1] = *(const bf16x8*)&sA[(arow + i * 16) * 64 + offk1];
            fb[i][0] = *(const bf16x8*)&sB[(brow + i * 16) * 64 + offk0];
            fb[i][1] = *(const bf16x8*)&sB[(brow + i * 16) * 64 + offk1];
        }
        #pragma unroll
        for (int i = 0; i < 4; ++i)
            #pragma unroll
            for (int j = 0; j < 4; ++j) {
                acc[i][j] = __builtin_amdgcn_mfma_f32_16x16x32_bf16(fa[i][0], fb[j][0], acc[i][j], 0, 0, 0);
                acc[i][j] = __builtin_amdgcn_mfma_f32_16x16x32_bf16(fa[i][1], fb[j][1], acc[i][j], 0, 0, 0);
            }
        __syncthreads();
    }

    if (rawOut) {   // exact integer partial sums in fp32
        #pragma unroll
        for (int i = 0; i < 4; ++i)
            #pragma unroll
            for (int j = 0; j < 4; ++j)
                #pragma unroll
                for (int rr = 0; rr < 4; ++rr) {
                    int m = (int)bm + wr * 64 + i * 16 + qa * 4 + rr;
                    int n = (int)bn + wc * 64 + j * 16 + rA;
                    rawOut[(size_t)m * 2048 + n] = acc[i][j][rr];
                }
        return;
    }

    const double scale = sumW[0] * invDivW * extraScale;
    double hs = 0.0;
    #pragma unroll
    for (int i = 0; i < 4; ++i) {
        #pragma unroll
        for (int j = 0; j < 4; ++j) {
            #pragma unroll
            for (int rr = 0; rr < 4; ++rr) {
                // C/D layout: col = lane&15, row = (lane>>4)*4 + reg
                int m = (int)bm + wr * 64 + i * 16 + qa * 4 + rr;
                int n = (int)bn + wc * 64 + j * 16 + rA;
                size_t idx = (size_t)m * 2048 + n;
                double s = (double)acc[i][j][rr];
                if (addPlane) s += (double)addPlane[idx];
                double z = s * scale + (n < 2000 ? (double)bias[n] : -1.0);
                binOut[idx] = (int8_t)(z > 0.0 ? 1 : 0);
                if (n < 2000 && z > 0.0) hs += z;
            }
        }
    }
    if (habs) block_reduce_atomic_d(hs, habs);
}

// i8 GEMM C = A @ B^T, A:[8192][2048] {0,1}, B:[2048][2048] {+-1,0}.
// 128x128 tile, BK=128 (16 KB per matrix, XOR-swizzled 16B chunks; byte layout
// identical to the bf16 tile). mfma_i32_16x16x64_i8: lane quad q holds k=q*16+j.
// Double epilogue as gemm_bin; optional bf16 hOut (layer 4).
__global__ __launch_bounds__(256, 4) void gemm_i8(
    const int8_t* __restrict__ A, const int8_t* __restrict__ B,
    const double* __restrict__ sumW, double invDivW,
    const double* __restrict__ sumH, double invDivH,
    const float* __restrict__ bias,
    int8_t* __restrict__ binOut, bf16_t* __restrict__ hOut,
    double* __restrict__ habs)
{
    const int K = 2048;                           // bytes per row
    __shared__ __align__(16) int8_t sA[128 * 128];
    __shared__ __align__(16) int8_t sB[128 * 128];
    const int t = threadIdx.x;
    const int lane = t & 63;
    const int wave = t >> 6;
    const int wr = wave >> 1, wc = wave & 1;
    const int qa = lane >> 4, rA = lane & 15;
    const size_t bm = (size_t)blockIdx.y * 128, bn = (size_t)blockIdx.x * 128;

    i32x4 acc[4][4] = {};

    const int8_t* Abase = A + bm * (size_t)K;
    const int8_t* Bbase = B + bn * (size_t)K;

    const int swz = rA & 7;
    const int offb0 = ((0 + qa) ^ swz) * 16;      // frag 0: k in [0,64)
    const int offb1 = ((4 + qa) ^ swz) * 16;      // frag 1: k in [64,128)
    const int arow = wr * 64 + rA;
    const int brow = wc * 64 + rA;

    for (int k0 = 0; k0 < K; k0 += 128) {
        #pragma unroll
        for (int i = 0; i < 4; ++i) {
            int c = i * 256 + t;
            int row = c >> 3, cc = c & 7;
            int ccg = cc ^ (row & 7);
            GLD_LDS16(Abase + (size_t)row * K + k0 + ccg * 16, &sA[c * 16]);
        }
        #pragma unroll
        for (int i = 0; i < 4; ++i) {
            int c = i * 256 + t;
            int row = c >> 3, cc = c & 7;
            int ccg = cc ^ (row & 7);
            GLD_LDS16(Bbase + (size_t)row * K + k0 + ccg * 16, &sB[c * 16]);
        }
        __syncthreads();

        i32x4 fa[4][2], fb[4][2];
        #pragma unroll
        for (int i = 0; i < 4; ++i) {
            fa[i][0] = *(const i32x4*)&sA[(arow + i * 16) * 128 + offb0];
            fa[i][1] = *(const i32x4*)&sA[(arow + i * 16) * 128 + offb1];
            fb[i][0] = *(const i32x4*)&sB[(brow + i * 16) * 128 + offb0];
            fb[i][1] = *(const i32x4*)&sB[(brow + i * 16) * 128 + offb1];
        }
        #pragma unroll
        for (int i = 0; i < 4; ++i)
            #pragma unroll
            for (int j = 0; j < 4; ++j) {
                acc[i][j] = __builtin_amdgcn_mfma_i32_16x16x64_i8(fa[i][0], fb[j][0], acc[i][j], 0, 0, 0);
                acc[i][j] = __builtin_amdgcn_mfma_i32_16x16x64_i8(fa[i][1], fb[j][1], acc[i][j], 0, 0, 0);
            }
        __syncthreads();
    }

    const double scale = sumW[0] * invDivW * sumH[0] * invDivH;
    double hs = 0.0;
    #pragma unroll
    for (int i = 0; i < 4; ++i) {
        #pragma unroll
        for (int j = 0; j < 4; ++j) {
            #pragma unroll
            for (int rr = 0; rr < 4; ++rr) {
                int m = (int)bm + wr * 64 + i * 16 + qa * 4 + rr;
                int n = (int)bn + wc * 64 + j * 16 + rA;
                size_t idx = (size_t)m * 2048 + n;
                double z = (double)acc[i][j][rr] * scale +
                           (n < 2000 ? (double)bias[n] : -1.0);
                if (binOut) binOut[idx] = (int8_t)(z > 0.0 ? 1 : 0);
                if (hOut)   hOut[idx] = (bf16_t)(float)(z > 0.0 ? z : 0.0);
                if (n < 2000 && z > 0.0) hs += z;
            }
        }
    }
    if (habs) block_reduce_atomic_d(hs, habs);
}

// out[8192][10] = h4[:, :2000] @ W5.T + b5  (h4 bf16, memory-bound)
__global__ __launch_bounds__(256) void fc_final(
    const bf16_t* __restrict__ h4, const float* __restrict__ W5,
    const float* __restrict__ b5, float* __restrict__ out)
{
    const int r = blockIdx.x, t = threadIdx.x;
    float acc[10] = {};
    for (int k = t; k < 2000; k += 256) {
        float a = (float)h4[(size_t)r * 2048 + k];
        #pragma unroll
        for (int c = 0; c < 10; ++c) acc[c] += a * W5[c * 2000 + k];
    }
    __shared__ float red[4][10];
    #pragma unroll
    for (int c = 0; c < 10; ++c) {
        float v = acc[c];
        #pragma unroll
        for (int off = 32; off > 0; off >>= 1) v += __shfl_down(v, off);
        if ((t & 63) == 0) red[t >> 6][c] = v;
    }
    __syncthreads();
    if (t < 10) out[(size_t)r * 10 + t] = red[0][t] + red[1][t] + red[2][t] + red[3][t] + b5[t];
}

extern "C" void kernel_launch(void* const* d_in, const int* in_sizes, int n_in,
                              void* d_out, int out_size, void* d_ws, size_t ws_size,
                              hipStream_t stream)
{
    const float* x  = (const float*)d_in[0];
    const float* W1 = (const float*)d_in[1];
    const float* b1 = (const float*)d_in[2];
    const float* W2 = (const float*)d_in[3];
    const float* b2 = (const float*)d_in[4];
    const float* W3 = (const float*)d_in[5];
    const float* b3 = (const float*)d_in[6];
    const float* W4 = (const float*)d_in[7];
    const float* b4 = (const float*)d_in[8];
    const float* W5 = (const float*)d_in[9];
    const float* b5 = (const float*)d_in[10];
    float* out = (float*)d_out;
    (void)ws_size; (void)in_sizes; (void)n_in; (void)out_size;

    const size_t PH = (size_t)8192 * 2048;

    // Workspace: 248.3 MiB (264 MiB proved safe in R3/R4; 516 faulted in R2)
    char* w = (char*)d_ws;
    double* scD = (double*)w;                     // [0..3]=sum|W1..4|, [4..6]=sum h1..3
    size_t off = 256;
    bf16_t* XLi = (bf16_t*)(w + off); off += (size_t)8192 * 6144 * 2;  // 96 MiB
    bf16_t* XLr = (bf16_t*)(w + off); off += (size_t)8192 * 3072 * 2;  // 48 MiB
    bf16_t* sW1 = (bf16_t*)(w + off); off += (size_t)2048 * 6144 * 2;  // 24 MiB [s|s]
    float*  Ti  = (float*)(w + off);  off += PH * 4;                   // 64 MiB
    int8_t* p0  = (int8_t*)(w + off); off += PH;                       // 16 MiB
    // Aliases into XLi (dead after the two L1 GEMMs): sW2/3/4 i8 (12 MiB) + p1 (16 MiB)
    int8_t* sW2 = (int8_t*)XLi;
    int8_t* sW3 = sW2 + (size_t)2048 * 2048;
    int8_t* sW4 = sW3 + (size_t)2048 * 2048;
    int8_t* p1  = sW4 + (size_t)2048 * 2048;
    bf16_t* h4  = (bf16_t*)Ti;                     // Ti dead after L1res epilogue

    hipMemsetAsync(w, 0, 256, stream);
    prep_w<<<2048, 256, 0, stream>>>(W1, 2000, 3072, sW1, 6144, 3072, 3072, scD + 0);
    prep_x<<<8192, 256, 0, stream>>>(x, XLi, XLr);

    dim3 grid(16, 64), blk(256);
    // L1 integer GEMM (exact): Ti = [d1*512|d0] @ [s|s]^T
    gemm_bin<<<grid, blk, 0, stream>>>(XLi, sW1, 6144, 6144, Ti, nullptr,
                                       nullptr, 0.0, 1.0, nullptr, nullptr, nullptr);
    // L1 residual GEMM + fused combine: z1 = mean|W1| * 2^-14 * (Ti + Sr) + b1
    gemm_bin<<<grid, blk, 0, stream>>>(XLr, sW1, 3072, 6144, nullptr, Ti,
                                       scD + 0, 1.0 / 6144000.0, 1.0 / 16384.0,
                                       b1, p0, scD + 4);
    // weight signs for layers 2-4 (i8) into the now-dead XLi region
    prep_w_i8<<<2048, 256, 0, stream>>>(W2, 2000, 2000, sW2, scD + 1);
    prep_w_i8<<<2048, 256, 0, stream>>>(W3, 2000, 2000, sW3, scD + 2);
    prep_w_i8<<<2048, 256, 0, stream>>>(W4, 2000, 2000, sW4, scD + 3);

    // Layers 2-4: exact i8 GEMMs, double epilogue
    gemm_i8<<<grid, blk, 0, stream>>>(p0, sW2,
                                      scD + 1, 1.0 / 4000000.0, scD + 4, 1.0 / 16384000.0,
                                      b2, p1, nullptr, scD + 5);
    gemm_i8<<<grid, blk, 0, stream>>>(p1, sW3,
                                      scD + 2, 1.0 / 4000000.0, scD + 5, 1.0 / 16384000.0,
                                      b3, p0, nullptr, scD + 6);
    gemm_i8<<<grid, blk, 0, stream>>>(p0, sW4,
                                      scD + 3, 1.0 / 4000000.0, scD + 6, 1.0 / 16384000.0,
                                      b4, nullptr, h4, nullptr);
    fc_final<<<8192, 256, 0, stream>>>(h4, W5, b5, out);
}

// Round 6
// 853.906 us; speedup vs baseline: 1.2467x; 1.0660x over previous
//
#include <hip/hip_runtime.h>
#include <hip/hip_bf16.h>
#include <stdint.h>

// Binarized MLP: B=8192, D_IN=3072, H=2000 (pad 2048), C=10.
// L1 (exact, bf16 MFMA): Q=round(x*2^14)=d1*512+d0 digits exact in bf16;
//   K=6144 GEMM [d1*512|d0]@[s|s]^T -> Ti exact; residual K=3072 GEMM fuses
//   z1 = mean|W1|*2^-14*(Ti+Sr)+b1 in double.
// Layers 2-4: i8 MFMA on {0,1}x{+-1} — exact i32, BK=128. h4 in bf16.
// R6: graph-node minimization — R3/R4/R5 all show a constant ~230us gap between
// modeled kernel time and dur_us (~12 nodes x ~20us launch/drain). Fuse the 5
// independent prep kernels into ONE dispatch (blockIdx-partitioned): 12 -> 8 nodes.
// GEMM numerics bit-identical to passing R5.
typedef __bf16 bf16_t;
typedef __attribute__((ext_vector_type(8))) __bf16 bf16x8;
typedef __attribute__((ext_vector_type(4))) float f32x4;
typedef __attribute__((ext_vector_type(4))) int i32x4;
typedef __attribute__((ext_vector_type(8))) char i8x8;

#define GLD_LDS16(g, l) __builtin_amdgcn_global_load_lds( \
    (__attribute__((address_space(1))) void*)(g), \
    (__attribute__((address_space(3))) void*)(l), 16, 0, 0)

__device__ __forceinline__ void block_reduce_atomic_d(double v, double* dst) {
    #pragma unroll
    for (int off = 32; off > 0; off >>= 1) v += __shfl_down(v, off);
    __shared__ double rb[4];
    const int t = threadIdx.x;
    if ((t & 63) == 0) rb[t >> 6] = v;
    __syncthreads();
    if (t == 0) atomicAdd(dst, rb[0] + rb[1] + rb[2] + rb[3]);
}

// --- fused prep: one dispatch, 16384 blocks ---
// blocks [0,2048)        : W1 -> bf16 [s|s] signs (ldS=6144) + sum|W1| -> scD[0]
// blocks [2048,4096)     : W2 -> i8 signs [2048][2048] + sum -> scD[1]
// blocks [4096,6144)     : W3 -> ...scD[2]
// blocks [6144,8192)     : W4 -> ...scD[3]
// blocks [8192,16384)    : x row -> XLi [d1*512|d0] bf16, XLr residual bf16
__device__ __forceinline__ void prep_w1_row(
    const float* __restrict__ W, int r, bf16_t* __restrict__ S, double* sumOut)
{
    const int t = threadIdx.x;
    double sl = 0.0;
    for (int cb = t * 8; cb < 3072; cb += 2048) {
        bf16x8 o;
        if (r < 2000) {
            #pragma unroll
            for (int j = 0; j < 8; ++j) {
                float v = W[(size_t)r * 3072 + cb + j];
                sl += (double)fabsf(v);
                o[j] = (bf16_t)(v > 0.f ? 1.f : (v < 0.f ? -1.f : 0.f));
            }
        } else {
            #pragma unroll
            for (int j = 0; j < 8; ++j) o[j] = (bf16_t)0.f;
        }
        *(bf16x8*)&S[(size_t)r * 6144 + cb] = o;
        *(bf16x8*)&S[(size_t)r * 6144 + 3072 + cb] = o;
    }
    block_reduce_atomic_d(sl, sumOut);
}

__device__ __forceinline__ void prep_wi8_row(
    const float* __restrict__ W, int r, int8_t* __restrict__ S, double* sumOut)
{
    const int t = threadIdx.x;
    const int cb = t * 8;
    double sl = 0.0;
    i8x8 o;
    if (r < 2000) {
        #pragma unroll
        for (int j = 0; j < 8; ++j) {
            int c = cb + j;
            float v = (c < 2000) ? W[(size_t)r * 2000 + c] : 0.f;
            sl += (double)fabsf(v);
            o[j] = (char)(v > 0.f ? 1 : (v < 0.f ? -1 : 0));
        }
    } else {
        #pragma unroll
        for (int j = 0; j < 8; ++j) o[j] = 0;
    }
    *(i8x8*)&S[(size_t)r * 2048 + cb] = o;
    block_reduce_atomic_d(sl, sumOut);
}

__device__ __forceinline__ void prep_x_row(
    const float* __restrict__ x, int r, bf16_t* __restrict__ XLi, bf16_t* __restrict__ XLr)
{
    const int t = threadIdx.x;
    for (int cb = t * 8; cb < 3072; cb += 2048) {
        float4 v0 = *(const float4*)&x[(size_t)r * 3072 + cb];
        float4 v1 = *(const float4*)&x[(size_t)r * 3072 + cb + 4];
        float xv[8] = {v0.x, v0.y, v0.z, v0.w, v1.x, v1.y, v1.z, v1.w};
        bf16x8 hi, lo, re;
        #pragma unroll
        for (int j = 0; j < 8; ++j) {
            int Q = (int)lrintf(xv[j] * 16384.f);           // x * 2^14
            int d0 = ((Q + 256) & 511) - 256;               // [-256,255], exact bf16
            int d1 = (Q - d0) / 512;                        // |d1|<=~182, exact bf16
            float rr = xv[j] - (float)Q * (1.f / 16384.f);  // exact (Sterbenz)
            hi[j] = (bf16_t)(float)(d1 * 512);              // exact (pow2 shift)
            lo[j] = (bf16_t)(float)d0;
            re[j] = (bf16_t)(rr * 16384.f);                 // in [-.5,.5]
        }
        *(bf16x8*)&XLi[(size_t)r * 6144 + cb]        = hi;
        *(bf16x8*)&XLi[(size_t)r * 6144 + 3072 + cb] = lo;
        *(bf16x8*)&XLr[(size_t)r * 3072 + cb]        = re;
    }
}

__global__ __launch_bounds__(256) void prep_all(
    const float* __restrict__ W1, const float* __restrict__ W2,
    const float* __restrict__ W3, const float* __restrict__ W4,
    const float* __restrict__ x,
    bf16_t* __restrict__ sW1, int8_t* __restrict__ sW2,
    int8_t* __restrict__ sW3, int8_t* __restrict__ sW4,
    bf16_t* __restrict__ XLi, bf16_t* __restrict__ XLr,
    double* __restrict__ scD)
{
    const int g = blockIdx.x;
    if      (g < 2048)  prep_w1_row(W1, g, sW1, scD + 0);
    else if (g < 4096)  prep_wi8_row(W2, g - 2048, sW2, scD + 1);
    else if (g < 6144)  prep_wi8_row(W3, g - 4096, sW3, scD + 2);
    else if (g < 8192)  prep_wi8_row(W4, g - 6144, sW4, scD + 3);
    else                prep_x_row(x, g - 8192, XLi, XLr);
}

// bf16 GEMM C = A @ B^T, 128x128x64 tiles. rawOut mode writes fp32 acc.
// Epilogue (double): z = sumW*invDivW*extraScale*(acc+addPlane?) + bias;
// binOut i8 {0,1}; atomic double sum(relu z).
__global__ __launch_bounds__(256, 4) void gemm_bin(
    const bf16_t* __restrict__ A, const bf16_t* __restrict__ B, int K, int ldB,
    float* __restrict__ rawOut,
    const float* __restrict__ addPlane,
    const double* __restrict__ sumW, double invDivW, double extraScale,
    const float* __restrict__ bias,
    int8_t* __restrict__ binOut,
    double* __restrict__ habs)
{
    __shared__ __align__(16) bf16_t sA[128 * 64];
    __shared__ __align__(16) bf16_t sB[128 * 64];
    const int t = threadIdx.x;
    const int lane = t & 63;
    const int wave = t >> 6;
    const int wr = wave >> 1, wc = wave & 1;
    const int qa = lane >> 4, rA = lane & 15;
    const size_t bm = (size_t)blockIdx.y * 128, bn = (size_t)blockIdx.x * 128;

    f32x4 acc[4][4] = {};

    const bf16_t* Abase = A + bm * (size_t)K;
    const bf16_t* Bbase = B + bn * (size_t)ldB;

    const int swz = rA & 7;
    const int offk0 = ((0 + qa) ^ swz) * 8;
    const int offk1 = ((4 + qa) ^ swz) * 8;
    const int arow = wr * 64 + rA;
    const int brow = wc * 64 + rA;

    for (int k0 = 0; k0 < K; k0 += 64) {
        #pragma unroll
        for (int i = 0; i < 4; ++i) {
            int c = i * 256 + t;
            int row = c >> 3, cc = c & 7;
            int ccg = cc ^ (row & 7);
            GLD_LDS16(Abase + (size_t)row * K + k0 + ccg * 8, &sA[c * 8]);
        }
        #pragma unroll
        for (int i = 0; i < 4; ++i) {
            int c = i * 256 + t;
            int row = c >> 3, cc = c & 7;
            int ccg = cc ^ (row & 7);
            GLD_LDS16(Bbase + (size_t)row * ldB + k0 + ccg * 8, &sB[c * 8]);
        }
        __syncthreads();

        bf16x8 fa[4][2], fb[4][2];
        #pragma unroll
        for (int i = 0; i < 4; ++i) {
            fa[i][0] = *(const bf16x8*)&sA[(arow + i * 16) * 64 + offk0];
            fa[i][1] = *(const bf16x8*)&sA[(arow + i * 16) * 64 + offk1];
            fb[i][0] = *(const bf16x8*)&sB[(brow + i * 16) * 64 + offk0];
            fb[i][1] = *(const bf16x8*)&sB[(brow + i * 16) * 64 + offk1];
        }
        #pragma unroll
        for (int i = 0; i < 4; ++i)
            #pragma unroll
            for (int j = 0; j < 4; ++j) {
                acc[i][j] = __builtin_amdgcn_mfma_f32_16x16x32_bf16(fa[i][0], fb[j][0], acc[i][j], 0, 0, 0);
                acc[i][j] = __builtin_amdgcn_mfma_f32_16x16x32_bf16(fa[i][1], fb[j][1], acc[i][j], 0, 0, 0);
            }
        __syncthreads();
    }

    if (rawOut) {   // exact integer partial sums in fp32
        #pragma unroll
        for (int i = 0; i < 4; ++i)
            #pragma unroll
            for (int j = 0; j < 4; ++j)
                #pragma unroll
                for (int rr = 0; rr < 4; ++rr) {
                    int m = (int)bm + wr * 64 + i * 16 + qa * 4 + rr;
                    int n = (int)bn + wc * 64 + j * 16 + rA;
                    rawOut[(size_t)m * 2048 + n] = acc[i][j][rr];
                }
        return;
    }

    const double scale = sumW[0] * invDivW * extraScale;
    double hs = 0.0;
    #pragma unroll
    for (int i = 0; i < 4; ++i) {
        #pragma unroll
        for (int j = 0; j < 4; ++j) {
            #pragma unroll
            for (int rr = 0; rr < 4; ++rr) {
                // C/D layout: col = lane&15, row = (lane>>4)*4 + reg
                int m = (int)bm + wr * 64 + i * 16 + qa * 4 + rr;
                int n = (int)bn + wc * 64 + j * 16 + rA;
                size_t idx = (size_t)m * 2048 + n;
                double s = (double)acc[i][j][rr];
                if (addPlane) s += (double)addPlane[idx];
                double z = s * scale + (n < 2000 ? (double)bias[n] : -1.0);
                binOut[idx] = (int8_t)(z > 0.0 ? 1 : 0);
                if (n < 2000 && z > 0.0) hs += z;
            }
        }
    }
    if (habs) block_reduce_atomic_d(hs, habs);
}

// i8 GEMM C = A @ B^T, A:[8192][2048] {0,1}, B:[2048][2048] {+-1,0}.
// 128x128 tile, BK=128, XOR-swizzled 16B chunks. Fragment loads split per
// k-half (32 live frag VGPRs instead of 64; integer sums order-independent).
__global__ __launch_bounds__(256, 4) void gemm_i8(
    const int8_t* __restrict__ A, const int8_t* __restrict__ B,
    const double* __restrict__ sumW, double invDivW,
    const double* __restrict__ sumH, double invDivH,
    const float* __restrict__ bias,
    int8_t* __restrict__ binOut, bf16_t* __restrict__ hOut,
    double* __restrict__ habs)
{
    const int K = 2048;                           // bytes per row
    __shared__ __align__(16) int8_t sA[128 * 128];
    __shared__ __align__(16) int8_t sB[128 * 128];
    const int t = threadIdx.x;
    const int lane = t & 63;
    const int wave = t >> 6;
    const int wr = wave >> 1, wc = wave & 1;
    const int qa = lane >> 4, rA = lane & 15;
    const size_t bm = (size_t)blockIdx.y * 128, bn = (size_t)blockIdx.x * 128;

    i32x4 acc[4][4] = {};

    const int8_t* Abase = A + bm * (size_t)K;
    const int8_t* Bbase = B + bn * (size_t)K;

    const int swz = rA & 7;
    const int offb0 = ((0 + qa) ^ swz) * 16;      // k-half 0: k in [0,64)
    const int offb1 = ((4 + qa) ^ swz) * 16;      // k-half 1: k in [64,128)
    const int arow = wr * 64 + rA;
    const int brow = wc * 64 + rA;

    for (int k0 = 0; k0 < K; k0 += 128) {
        #pragma unroll
        for (int i = 0; i < 4; ++i) {
            int c = i * 256 + t;
            int row = c >> 3, cc = c & 7;
            int ccg = cc ^ (row & 7);
            GLD_LDS16(Abase + (size_t)row * K + k0 + ccg * 16, &sA[c * 16]);
        }
        #pragma unroll
        for (int i = 0; i < 4; ++i) {
            int c = i * 256 + t;
            int row = c >> 3, cc = c & 7;
            int ccg = cc ^ (row & 7);
            GLD_LDS16(Bbase + (size_t)row * K + k0 + ccg * 16, &sB[c * 16]);
        }
        __syncthreads();

        {   // k-half 0
            i32x4 fa[4], fb[4];
            #pragma unroll
            for (int i = 0; i < 4; ++i) {
                fa[i] = *(const i32x4*)&sA[(arow + i * 16) * 128 + offb0];
                fb[i] = *(const i32x4*)&sB[(brow + i * 16) * 128 + offb0];
            }
            #pragma unroll
            for (int i = 0; i < 4; ++i)
                #pragma unroll
                for (int j = 0; j < 4; ++j)
                    acc[i][j] = __builtin_amdgcn_mfma_i32_16x16x64_i8(fa[i], fb[j], acc[i][j], 0, 0, 0);
        }
        {   // k-half 1
            i32x4 fa[4], fb[4];
            #pragma unroll
            for (int i = 0; i < 4; ++i) {
                fa[i] = *(const i32x4*)&sA[(arow + i * 16) * 128 + offb1];
                fb[i] = *(const i32x4*)&sB[(brow + i * 16) * 128 + offb1];
            }
            #pragma unroll
            for (int i = 0; i < 4; ++i)
                #pragma unroll
                for (int j = 0; j < 4; ++j)
                    acc[i][j] = __builtin_amdgcn_mfma_i32_16x16x64_i8(fa[i], fb[j], acc[i][j], 0, 0, 0);
        }
        __syncthreads();
    }

    const double scale = sumW[0] * invDivW * sumH[0] * invDivH;
    double hs = 0.0;
    #pragma unroll
    for (int i = 0; i < 4; ++i) {
        #pragma unroll
        for (int j = 0; j < 4; ++j) {
            #pragma unroll
            for (int rr = 0; rr < 4; ++rr) {
                int m = (int)bm + wr * 64 + i * 16 + qa * 4 + rr;
                int n = (int)bn + wc * 64 + j * 16 + rA;
                size_t idx = (size_t)m * 2048 + n;
                double z = (double)acc[i][j][rr] * scale +
                           (n < 2000 ? (double)bias[n] : -1.0);
                if (binOut) binOut[idx] = (int8_t)(z > 0.0 ? 1 : 0);
                if (hOut)   hOut[idx] = (bf16_t)(float)(z > 0.0 ? z : 0.0);
                if (n < 2000 && z > 0.0) hs += z;
            }
        }
    }
    if (habs) block_reduce_atomic_d(hs, habs);
}

// out[8192][10] = h4[:, :2000] @ W5.T + b5  (h4 bf16, memory-bound)
__global__ __launch_bounds__(256) void fc_final(
    const bf16_t* __restrict__ h4, const float* __restrict__ W5,
    const float* __restrict__ b5, float* __restrict__ out)
{
    const int r = blockIdx.x, t = threadIdx.x;
    float acc[10] = {};
    for (int k = t; k < 2000; k += 256) {
        float a = (float)h4[(size_t)r * 2048 + k];
        #pragma unroll
        for (int c = 0; c < 10; ++c) acc[c] += a * W5[c * 2000 + k];
    }
    __shared__ float red[4][10];
    #pragma unroll
    for (int c = 0; c < 10; ++c) {
        float v = acc[c];
        #pragma unroll
        for (int off = 32; off > 0; off >>= 1) v += __shfl_down(v, off);
        if ((t & 63) == 0) red[t >> 6][c] = v;
    }
    __syncthreads();
    if (t < 10) out[(size_t)r * 10 + t] = red[0][t] + red[1][t] + red[2][t] + red[3][t] + b5[t];
}

extern "C" void kernel_launch(void* const* d_in, const int* in_sizes, int n_in,
                              void* d_out, int out_size, void* d_ws, size_t ws_size,
                              hipStream_t stream)
{
    const float* x  = (const float*)d_in[0];
    const float* W1 = (const float*)d_in[1];
    const float* b1 = (const float*)d_in[2];
    const float* W2 = (const float*)d_in[3];
    const float* b2 = (const float*)d_in[4];
    const float* W3 = (const float*)d_in[5];
    const float* b3 = (const float*)d_in[6];
    const float* W4 = (const float*)d_in[7];
    const float* b4 = (const float*)d_in[8];
    const float* W5 = (const float*)d_in[9];
    const float* b5 = (const float*)d_in[10];
    float* out = (float*)d_out;
    (void)ws_size; (void)in_sizes; (void)n_in; (void)out_size;

    const size_t PH = (size_t)8192 * 2048;

    // Workspace: 248.3 MiB (264 proved safe R3/R4; 516 faulted R2)
    char* w = (char*)d_ws;
    double* scD = (double*)w;                     // [0..3]=sum|W1..4|, [4..6]=sum h1..3
    size_t off = 256;
    bf16_t* XLi = (bf16_t*)(w + off); off += (size_t)8192 * 6144 * 2;  // 96 MiB
    bf16_t* XLr = (bf16_t*)(w + off); off += (size_t)8192 * 3072 * 2;  // 48 MiB
    bf16_t* sW1 = (bf16_t*)(w + off); off += (size_t)2048 * 6144 * 2;  // 24 MiB [s|s]
    float*  Ti  = (float*)(w + off);  off += PH * 4;                   // 64 MiB
    int8_t* p0  = (int8_t*)(w + off); off += PH;                       // 16 MiB
    // sW2/3/4 + p1 live in their own region AFTER p0? No — alias the dead XLi
    // is NOT possible anymore (prep_all writes sW2-4 while XLi is still live).
    // Move sW2-4 to dedicated space; p1 still aliases XLi (dead after L1 GEMMs).
    int8_t* sW2 = (int8_t*)(w + off); off += (size_t)2048 * 2048;      // 4 MiB
    int8_t* sW3 = (int8_t*)(w + off); off += (size_t)2048 * 2048;      // 4 MiB
    int8_t* sW4 = (int8_t*)(w + off); off += (size_t)2048 * 2048;      // 4 MiB
    int8_t* p1  = (int8_t*)XLi;                    // XLi dead after L1 GEMMs
    bf16_t* h4  = (bf16_t*)Ti;                     // Ti dead after L1res epilogue
    // total: 256 B + 96+48+24+64+16+12 = 260.3 MiB < 264 proven-safe

    hipMemsetAsync(w, 0, 256, stream);
    // one fused prep dispatch: W1 signs (bf16 [s|s]), W2-4 signs (i8), x limbs
    prep_all<<<16384, 256, 0, stream>>>(W1, W2, W3, W4, x,
                                        sW1, sW2, sW3, sW4, XLi, XLr, scD);

    dim3 grid(16, 64), blk(256);
    // L1 integer GEMM (exact): Ti = [d1*512|d0] @ [s|s]^T
    gemm_bin<<<grid, blk, 0, stream>>>(XLi, sW1, 6144, 6144, Ti, nullptr,
                                       nullptr, 0.0, 1.0, nullptr, nullptr, nullptr);
    // L1 residual GEMM + fused combine: z1 = mean|W1| * 2^-14 * (Ti + Sr) + b1
    gemm_bin<<<grid, blk, 0, stream>>>(XLr, sW1, 3072, 6144, nullptr, Ti,
                                       scD + 0, 1.0 / 6144000.0, 1.0 / 16384.0,
                                       b1, p0, scD + 4);

    // Layers 2-4: exact i8 GEMMs, double epilogue
    gemm_i8<<<grid, blk, 0, stream>>>(p0, sW2,
                                      scD + 1, 1.0 / 4000000.0, scD + 4, 1.0 / 16384000.0,
                                      b2, p1, nullptr, scD + 5);
    gemm_i8<<<grid, blk, 0, stream>>>(p1, sW3,
                                      scD + 2, 1.0 / 4000000.0, scD + 5, 1.0 / 16384000.0,
                                      b3, p0, nullptr, scD + 6);
    gemm_i8<<<grid, blk, 0, stream>>>(p0, sW4,
                                      scD + 3, 1.0 / 4000000.0, scD + 6, 1.0 / 16384000.0,
                                      b4, nullptr, h4, nullptr);
    fc_final<<<8192, 256, 0, stream>>>(h4, W5, b5, out);
}